// Round 9
// baseline (39.626 us; speedup 1.0000x reference)
//
#include <hip/hip_runtime.h>
#include <hip/hip_bf16.h>

#define BB   4
#define CC   128
#define HH   192
#define WWd  192
#define HWp  (HH*WWd)      // 36864
#define OO   128
#define KK   7
#define NPIX (BB*HWp)      // 147456

typedef short bf16x8 __attribute__((ext_vector_type(8)));
typedef float f32x4  __attribute__((ext_vector_type(4)));

static __device__ __forceinline__ unsigned f2bf(float f) {
    union { __hip_bfloat16 h; unsigned short u; } cvt;
    cvt.h = __float2bfloat16(f);
    return (unsigned)cvt.u;
}

// ---- prep: Wsum[o][c] = sum_k kernel_w[o*7+k, c] -> bf16 in MFMA A-frag order;
//      bsum[o] = sum_k kernel_b[o*7+k] (fp32).  (validated round 3: mt8 mapping)
__global__ __launch_bounds__(256) void prep_kernel(const float* __restrict__ kw,
                                                   const float* __restrict__ kb,
                                                   unsigned short* __restrict__ wfrag,
                                                   float* __restrict__ bsum) {
    int tid = blockIdx.x * 256 + threadIdx.x;   // 0..16383
    int o = tid >> 7, c = tid & 127;
    float s = 0.f;
#pragma unroll
    for (int k = 0; k < KK; ++k) s += kw[(o*KK + k)*CC + c];
    // conv reads: afrag[mt][ks] lane l elem j <-> o = mt*16+(l&15), c = ks*32+(l>>4)*8+j
    int mt8 = o >> 4, lo = o & 15;
    int ks = c >> 5, g = (c >> 3) & 3, j = c & 7;
    int idx = (((mt8*4 + ks)*64) + (lo + 16*g))*8 + j;
    wfrag[idx] = (unsigned short)f2bf(s);
    if (c == 0) {
        float bs = 0.f;
#pragma unroll
        for (int k = 0; k < KK; ++k) bs += kb[o*KK + k];
        bsum[o] = bs;
    }
}

// ---- main: NO LDS, NO barriers, fully independent waves.
// Wave = 16 pixels x all 128 outputs. Load assignment IS the B-fragment layout:
// lane (g4,lo16), load (ks,j): c = g4*8 + j + 32*ks, pix = lo16  ->  b[ks][j] directly.
// afrag hoisted once (64 VGPR); csum in-register + 2 shfl_xor; plain coalesced stores.
__global__ __launch_bounds__(256) void conv_kernel(const float* __restrict__ x,
                                                   const unsigned short* __restrict__ wfrag,
                                                   const float* __restrict__ bsum,
                                                   float* __restrict__ out) {
    const int t = threadIdx.x;
    const int w = t >> 6;            // wave 0..3: pixel sub-tile
    const int l = t & 63;
    const int lo16 = l & 15, g4 = l >> 4;

    const int pixBase = blockIdx.x * 64 + w * 16;   // batch-aligned (HWp % 64 == 0)
    const int bIdx = pixBase / HWp;
    const int hw   = pixBase - bIdx * HWp;
    const float* xb = x + (size_t)bIdx * CC * HWp + hw + lo16 + (size_t)(g4 * 8) * HWp;

    // A-fragments (Wsum) hoisted: 8 m-tiles x 4 k-steps; wfrag is L1/L2-resident
    bf16x8 afrag[8][4];
#pragma unroll
    for (int mt = 0; mt < 8; ++mt)
#pragma unroll
        for (int ks = 0; ks < 4; ++ks)
            afrag[mt][ks] = *reinterpret_cast<const bf16x8*>(
                wfrag + ((size_t)(mt*4 + ks)*64 + l)*8);

    // 32 coalesced loads; each instr = 4 x 64B fully-used segments (validated R3: no overfetch)
    float v[4][8];
#pragma unroll
    for (int ks = 0; ks < 4; ++ks)
#pragma unroll
        for (int j = 0; j < 8; ++j)
            v[ks][j] = xb[(size_t)(ks*32 + j) * HWp];

    // pack B-fragments + in-register channel sum
    float csum = 0.f;
    bf16x8 b[4];
#pragma unroll
    for (int ks = 0; ks < 4; ++ks)
#pragma unroll
        for (int j = 0; j < 8; ++j) {
            csum += v[ks][j];
            b[ks][j] = (short)f2bf(v[ks][j]);
        }
    csum += __shfl_xor(csum, 16);    // quarters hold disjoint 32-channel sets
    csum += __shfl_xor(csum, 32);

    f32x4 acc[8];
#pragma unroll
    for (int mt = 0; mt < 8; ++mt) acc[mt] = (f32x4){0.f, 0.f, 0.f, 0.f};
#pragma unroll
    for (int ks = 0; ks < 4; ++ks)
#pragma unroll
        for (int mt = 0; mt < 8; ++mt)
            acc[mt] = __builtin_amdgcn_mfma_f32_16x16x32_bf16(afrag[mt][ks], b[ks], acc[mt], 0, 0, 0);

    // Epilogue: out[o,p] = s[p]*(dot + bsum[o]); D row = g4*4+r, col = lo16 (validated R3)
    float* ob = out + (size_t)bIdx * OO * HWp + hw + lo16;
#pragma unroll
    for (int mt = 0; mt < 8; ++mt) {
        const int o0 = mt*16 + g4*4;
        const float4 bs4 = *reinterpret_cast<const float4*>(bsum + o0);
#pragma unroll
        for (int r = 0; r < 4; ++r) {
            const float bsv = (r == 0) ? bs4.x : (r == 1) ? bs4.y : (r == 2) ? bs4.z : bs4.w;
            ob[(size_t)(o0 + r) * HWp] = (acc[mt][r] + bsv) * csum;
        }
    }
}

extern "C" void kernel_launch(void* const* d_in, const int* in_sizes, int n_in,
                              void* d_out, int out_size, void* d_ws, size_t ws_size,
                              hipStream_t stream) {
    const float* x  = (const float*)d_in[0];
    // d_in[1] offsets, d_in[2] tumor_center: mathematically dead (grid_sample on 1x1 input)
    const float* kw = (const float*)d_in[3];
    const float* kb = (const float*)d_in[4];
    float* outp = (float*)d_out;

    unsigned short* wfrag = (unsigned short*)d_ws;                 // 128*128 bf16 = 32 KB
    float* bsum = (float*)((char*)d_ws + 32768);                   // 128 f32

    prep_kernel<<<dim3(64), dim3(256), 0, stream>>>(kw, kb, wfrag, bsum);
    conv_kernel<<<dim3(NPIX / 64), dim3(256), 0, stream>>>(x, wfrag, bsum, outp);
}